// Round 1
// baseline (29.744 us; speedup 1.0000x reference)
//
#include <hip/hip_runtime.h>
#include <hip/hip_bf16.h>
#include <cstdint>
#include <cstddef>

// Problem constants (from reference)
#define NN     50000   // nodes
#define FIN    128
#define FOUT   128
#define FLIN   64
#define BM     32      // rows per block
#define GATE_PACK_ELEMS 49152   // 24 col-tiles * 4 kb * 64 lanes * 8
#define LIN_PACK_ELEMS  8192    // 4 col-tiles * 4 kb * 64 lanes * 8

typedef __attribute__((ext_vector_type(4))) float f32x4;
typedef __attribute__((ext_vector_type(8))) short s16x8;

__device__ __forceinline__ unsigned short f2bf(float f) {
    union { float f; unsigned int u; } v; v.f = f;
    unsigned int r = v.u + 0x7FFFu + ((v.u >> 16) & 1u);   // round-to-nearest-even
    return (unsigned short)(r >> 16);
}

__device__ __forceinline__ float fsigmoid(float x) {
    x = fminf(fmaxf(x, -30.f), 30.f);
    return __builtin_amdgcn_rcpf(1.f + __expf(-x));
}
__device__ __forceinline__ float ftanh(float x) {
    x = fminf(fmaxf(x, -15.f), 15.f);
    float e2 = __expf(2.f * x);
    return (e2 - 1.f) * __builtin_amdgcn_rcpf(e2 + 1.f);
}

// ---------------------------------------------------------------------------
// Kernel 0: pack Wx[{0,2,3}] (gates i, c, o) and lin_W into bf16 MFMA
// B-fragment order: elem[((ct*4+kb)*64+lane)*8 + i] = W[kb*32+(lane>>4)*8+i][col]
// where col = (ct%8)*16 + (lane&15) within the gate (ct/8 selects the gate).
// ---------------------------------------------------------------------------
__global__ void pack_weights(const float* __restrict__ Wx,
                             const float* __restrict__ linW,
                             unsigned short* __restrict__ wp) {
    int t = blockIdx.x * blockDim.x + threadIdx.x;
    if (t < GATE_PACK_ELEMS) {
        int i    = t & 7;
        int lane = (t >> 3) & 63;
        int kb   = (t >> 9) & 3;
        int ct   = t >> 11;            // 0..23
        int gg   = ct >> 3;            // 0..2 -> gates i, c, o
        int ctl  = ct & 7;
        int g    = (gg == 0) ? 0 : (gg == 1 ? 2 : 3);
        int k    = kb * 32 + (lane >> 4) * 8 + i;
        int col  = ctl * 16 + (lane & 15);
        wp[t] = f2bf(Wx[g * (FIN * FOUT) + k * FOUT + col]);
    } else if (t < GATE_PACK_ELEMS + LIN_PACK_ELEMS) {
        int u    = t - GATE_PACK_ELEMS;
        int i    = u & 7;
        int lane = (u >> 3) & 63;
        int kb   = (u >> 9) & 3;
        int ct   = u >> 11;            // 0..3
        int k    = kb * 32 + (lane >> 4) * 8 + i;
        int col  = ct * 16 + (lane & 15);
        wp[t] = f2bf(linW[k * FLIN + col]);
    }
}

// ---------------------------------------------------------------------------
// Main fused kernel: 32 rows / block, 256 threads (4 waves).
// Phase 1: G = x_tile @ [Wx_i | Wx_c | Wx_o]  (bf16 MFMA, K=128, N=384)
//   wave w owns col-tiles {2w, 2w+1} OF EACH gate -> gate math is lane-local.
// Epilogue 1: LSTM cell from zero state, h = relu(O * tanh(C)) -> LDS bf16.
// Phase 2: out = h_tile @ lin_W + lin_b  (K=128, N=64), store f32.
// ---------------------------------------------------------------------------
__global__ __launch_bounds__(256) void gclstm_fused(
    const float* __restrict__ x,
    const unsigned short* __restrict__ wp,      // packed gates; +GATE_PACK_ELEMS = lin
    const float* __restrict__ b_gate,           // (4,1,128)
    const float* __restrict__ w_c,              // (3,1,128)
    const float* __restrict__ cheb_b,           // (4,128)
    const float* __restrict__ lin_b,            // (64)
    float* __restrict__ out)                    // (NN,64)
{
    __shared__ __align__(16) unsigned char ldsx[BM * 256];  // 32 rows x 128 bf16, swizzled
    __shared__ __align__(16) unsigned char ldsh[BM * 256];

    const int tid  = threadIdx.x;
    const int w    = tid >> 6;       // wave 0..3
    const int lane = tid & 63;
    const int lg   = lane >> 4;      // 0..3
    const int lc   = lane & 15;
    const long m0  = (long)blockIdx.x * BM;

    // ---- stage x tile -> LDS bf16, XOR-swizzled (G4: [R][128]bf16 fix) ----
    #pragma unroll
    for (int it = 0; it < 4; ++it) {
        int idx = tid + it * 256;    // float4 index: row = idx/32, c4 = idx%32
        int row = idx >> 5;
        int c4  = idx & 31;
        f32x4 v = {0.f, 0.f, 0.f, 0.f};
        if (m0 + row < NN)
            v = *(const f32x4*)(x + (m0 + row) * FIN + c4 * 4);
        unsigned int lo = (unsigned)f2bf(v.x) | ((unsigned)f2bf(v.y) << 16);
        unsigned int hi = (unsigned)f2bf(v.z) | ((unsigned)f2bf(v.w) << 16);
        int byte = (row * 256 + c4 * 8) ^ ((row & 7) << 4);
        *(uint2*)(ldsx + byte) = make_uint2(lo, hi);
    }
    __syncthreads();

    // ---- phase 1: load A fragments (rows rt*16+lc, k = kb*32+lg*8+0..7) ----
    s16x8 afr[2][4];
    #pragma unroll
    for (int rt = 0; rt < 2; ++rt)
        #pragma unroll
        for (int kb = 0; kb < 4; ++kb) {
            int row  = rt * 16 + lc;
            int byte = (row * 256 + kb * 64 + lg * 16) ^ ((row & 7) << 4);
            afr[rt][kb] = *(const s16x8*)(ldsx + byte);
        }

    f32x4 acc[2][3][2];
    #pragma unroll
    for (int rt = 0; rt < 2; ++rt)
        #pragma unroll
        for (int gg = 0; gg < 3; ++gg)
            #pragma unroll
            for (int c2 = 0; c2 < 2; ++c2)
                acc[rt][gg][c2] = (f32x4){0.f, 0.f, 0.f, 0.f};

    #pragma unroll
    for (int gg = 0; gg < 3; ++gg) {
        #pragma unroll
        for (int c2 = 0; c2 < 2; ++c2) {
            int ct = gg * 8 + 2 * w + c2;
            const unsigned short* bp = wp + (size_t)ct * 2048 + (size_t)lane * 8;
            s16x8 b0 = *(const s16x8*)(bp);
            s16x8 b1 = *(const s16x8*)(bp + 512);
            s16x8 b2 = *(const s16x8*)(bp + 1024);
            s16x8 b3 = *(const s16x8*)(bp + 1536);
            #pragma unroll
            for (int rt = 0; rt < 2; ++rt) {
                acc[rt][gg][c2] = __builtin_amdgcn_mfma_f32_16x16x32_bf16(afr[rt][0], b0, acc[rt][gg][c2], 0, 0, 0);
                acc[rt][gg][c2] = __builtin_amdgcn_mfma_f32_16x16x32_bf16(afr[rt][1], b1, acc[rt][gg][c2], 0, 0, 0);
                acc[rt][gg][c2] = __builtin_amdgcn_mfma_f32_16x16x32_bf16(afr[rt][2], b2, acc[rt][gg][c2], 0, 0, 0);
                acc[rt][gg][c2] = __builtin_amdgcn_mfma_f32_16x16x32_bf16(afr[rt][3], b3, acc[rt][gg][c2], 0, 0, 0);
            }
        }
    }

    // ---- epilogue 1: LSTM cell (H=C=0 initial state), h -> LDS bf16 ----
    #pragma unroll
    for (int c2 = 0; c2 < 2; ++c2) {
        int col = (2 * w + c2) * 16 + lc;          // 0..127
        float bi  = cheb_b[0 * 128 + col] + b_gate[0 * 128 + col];
        float bc  = cheb_b[2 * 128 + col] + b_gate[2 * 128 + col];
        float bo  = cheb_b[3 * 128 + col] + b_gate[3 * 128 + col];
        float wco = w_c[2 * 128 + col];
        #pragma unroll
        for (int rt = 0; rt < 2; ++rt) {
            #pragma unroll
            for (int r = 0; r < 4; ++r) {
                float I = fsigmoid(acc[rt][0][c2][r] + bi);
                float T = ftanh(acc[rt][1][c2][r] + bc);
                float C = I * T;
                float O = fsigmoid(acc[rt][2][c2][r] + wco * C + bo);
                float h = fmaxf(O * ftanh(C), 0.f);
                int row  = rt * 16 + lg * 4 + r;
                int byte = (row * 256 + col * 2) ^ ((row & 7) << 4);
                *(unsigned short*)(ldsh + byte) = f2bf(h);
            }
        }
    }
    __syncthreads();

    // ---- phase 2: out = h @ lin_W + lin_b ----
    const int rt2 = w & 1;                 // row tile
    const int ct0 = (w >> 1) * 2;          // col tiles {ct0, ct0+1}
    s16x8 ha[4];
    #pragma unroll
    for (int kb = 0; kb < 4; ++kb) {
        int row  = rt2 * 16 + lc;
        int byte = (row * 256 + kb * 64 + lg * 16) ^ ((row & 7) << 4);
        ha[kb] = *(const s16x8*)(ldsh + byte);
    }
    f32x4 acc2[2];
    #pragma unroll
    for (int c2 = 0; c2 < 2; ++c2) {
        acc2[c2] = (f32x4){0.f, 0.f, 0.f, 0.f};
        int ct = ct0 + c2;
        const unsigned short* bp = wp + GATE_PACK_ELEMS + (size_t)ct * 2048 + (size_t)lane * 8;
        acc2[c2] = __builtin_amdgcn_mfma_f32_16x16x32_bf16(ha[0], *(const s16x8*)(bp),        acc2[c2], 0, 0, 0);
        acc2[c2] = __builtin_amdgcn_mfma_f32_16x16x32_bf16(ha[1], *(const s16x8*)(bp + 512),  acc2[c2], 0, 0, 0);
        acc2[c2] = __builtin_amdgcn_mfma_f32_16x16x32_bf16(ha[2], *(const s16x8*)(bp + 1024), acc2[c2], 0, 0, 0);
        acc2[c2] = __builtin_amdgcn_mfma_f32_16x16x32_bf16(ha[3], *(const s16x8*)(bp + 1536), acc2[c2], 0, 0, 0);
    }
    #pragma unroll
    for (int c2 = 0; c2 < 2; ++c2) {
        int col  = (ct0 + c2) * 16 + lc;
        float lb = lin_b[col];
        #pragma unroll
        for (int r = 0; r < 4; ++r) {
            long row = m0 + rt2 * 16 + lg * 4 + r;
            if (row < NN)
                out[row * FLIN + col] = acc2[c2][r] + lb;
        }
    }
}

extern "C" void kernel_launch(void* const* d_in, const int* in_sizes, int n_in,
                              void* d_out, int out_size, void* d_ws, size_t ws_size,
                              hipStream_t stream) {
    const float* x      = (const float*)d_in[0];
    // d_in[1] edge_index, d_in[2] edge_weight, d_in[6] cheb_W: dead (H=C=0)
    const float* Wx     = (const float*)d_in[3];
    const float* b_gate = (const float*)d_in[4];
    const float* w_c    = (const float*)d_in[5];
    const float* cheb_b = (const float*)d_in[7];
    const float* lin_W  = (const float*)d_in[8];
    const float* lin_b  = (const float*)d_in[9];
    float* out          = (float*)d_out;
    unsigned short* wp  = (unsigned short*)d_ws;   // 114688 B used

    pack_weights<<<(GATE_PACK_ELEMS + LIN_PACK_ELEMS + 255) / 256, 256, 0, stream>>>(Wx, lin_W, wp);

    int grid = (NN + BM - 1) / BM;   // 1563
    gclstm_fused<<<grid, 256, 0, stream>>>(x, wp, b_gate, w_c, cheb_b, lin_b, out);
}